// Round 3
// baseline (481.954 us; speedup 1.0000x reference)
//
#include <hip/hip_runtime.h>

#define L_DIM 4096
#define C_DIM 256
#define NB 4

typedef __bf16 bf16x8 __attribute__((ext_vector_type(8)));
typedef float f32x4 __attribute__((ext_vector_type(4)));

#define GLB __attribute__((address_space(1)))
#define AS3 __attribute__((address_space(3)))

// ---------------- K0: zero the small workspace accumulators ----------------
// (only 320 KB of d_ws used in total — previous sessions prove this fits)
__global__ void init_ws(float* __restrict__ rsum, float* __restrict__ csum,
                        unsigned int* __restrict__ colmax,
                        unsigned long long* __restrict__ rowpack) {
    int i = blockIdx.x * 256 + threadIdx.x;
    if (i < NB * L_DIM) { rsum[i] = 0.f; csum[i] = 0.f; colmax[i] = 0u; rowpack[i] = 0ull; }
}

// ---------------- K0b: f32 -> bf16 pre-conversion into the conf stash ------
// abf/bbf live in the LAST 16.8 MB of out_conf (n=3 rows 3072..4095). They
// are consumed by gemm<true,0> and gemm<true,1>-main, then overwritten with
// final conf values by gemm<false,1>-tail. Stream order removes all races.
__global__ __launch_bounds__(256) void conv_k(const float* __restrict__ f0,
                                              const float* __restrict__ f1,
                                              __bf16* __restrict__ abf,
                                              __bf16* __restrict__ bbf) {
    int i = blockIdx.x * 256 + threadIdx.x;   // 2048 x-blocks cover NB*L*C/8
    const float* in = blockIdx.y ? f1 : f0;
    __bf16* out = blockIdx.y ? bbf : abf;
    const float4* p = (const float4*)in + (size_t)i * 2;
    float4 a = p[0], b = p[1];
    bf16x8 v;
    v[0]=(__bf16)a.x; v[1]=(__bf16)a.y; v[2]=(__bf16)a.z; v[3]=(__bf16)a.w;
    v[4]=(__bf16)b.x; v[5]=(__bf16)b.y; v[6]=(__bf16)b.z; v[7]=(__bf16)b.w;
    *(bf16x8*)&out[(size_t)i * 8] = v;
}

// ---------------- GEMM (recompute) template ----------------
// PRE:  true  -> bf16 inputs staged via global_load_lds (linear LDS dest,
//                XOR-swizzled global source + XOR-swizzled ds_read: rule #21)
//       false -> f32 inputs, reg-convert staging (padded [128][72] LDS)
// MODE: 0 -> e=exp(sim*scale), fused row/col atomicAdd sums (no matrix write)
//       1 -> conf = exp(2*scale*sim)*invr*invc, write conf, fused maxes
// Grid decode per instantiation:
//   <true,0>  : grid (32,32,NB)  n=z, tl=y                (all 4096 tiles)
//   <true,1>  : grid (32,120,1)  main tiles, skip n=3 tl>=24 (stash region)
//   <false,1> : grid (32,8,1)    tail tiles n=3 tl=24+y   (stash region)
template<bool PRE, int MODE>
__global__ __launch_bounds__(256) void gemm_pass(
        const float* __restrict__ f0, const float* __restrict__ f1,
        const __bf16* __restrict__ a_bf, const __bf16* __restrict__ b_bf,
        float* __restrict__ E,
        float* __restrict__ rsum, float* __restrict__ csum,
        unsigned long long* __restrict__ rowpack, unsigned int* __restrict__ colmax) {
    const int ts = blockIdx.x;
    int n, tl;
    if constexpr (MODE == 0) {
        n = blockIdx.z; tl = blockIdx.y;
    } else if constexpr (PRE) {
        int y = blockIdx.y;
        if (y < 96) { n = y >> 5; tl = y & 31; }
        else        { n = 3; tl = y - 96; }        // tl 0..23
    } else {
        n = 3; tl = 24 + blockIdx.y;               // tl 24..31 (stash tiles)
    }

    constexpr int LDST = PRE ? 64 : 72;
    __shared__ __bf16 Al[128 * LDST];
    __shared__ __bf16 Bl[128 * LDST];

    const int t    = threadIdx.x;
    const int lane = t & 63;
    const int wave = t >> 6;
    const int wm   = wave >> 1, wn = wave & 1;
    const int q    = lane >> 4;
    const int l15  = lane & 15;

    const float* A = f0 + ((size_t)n * L_DIM + (size_t)tl * 128) * C_DIM;
    const float* B = f1 + ((size_t)n * L_DIM + (size_t)ts * 128) * C_DIM;
    const __bf16* gA = a_bf + ((size_t)n * L_DIM + (size_t)tl * 128) * C_DIM;
    const __bf16* gB = b_bf + ((size_t)n * L_DIM + (size_t)ts * 128) * C_DIM;

    f32x4 acc[4][4] = {};

    const int r8 = t >> 3;        // fallback staging row group
    const int c8 = t & 7;         // fallback staging chunk
    const int lr = lane >> 3;     // PRE staging row-in-chunk (== row & 7)
    // T2/rule#21: inverse-swizzled GLOBAL source column so linear LDS write +
    // swizzled ds_read compose to identity. slot' = slot ^ (row&7).
    const int lc = ((lane & 7) ^ lr) * 8;   // bf16 elems within 64-col slab

    for (int kt = 0; kt < C_DIM; kt += 64) {
        if constexpr (PRE) {
            // ---- direct global->LDS staging, 16B/lane, linear LDS dest ----
            #pragma unroll
            for (int i = 0; i < 4; ++i) {
                const int chunk = wave * 4 + i;       // 1KB LDS chunk per call
                const int row = chunk * 8 + lr;
                __builtin_amdgcn_global_load_lds(
                    (const GLB void*)(gA + (size_t)row * C_DIM + kt + lc),
                    (AS3 void*)&Al[chunk * 512], 16, 0, 0);
                __builtin_amdgcn_global_load_lds(
                    (const GLB void*)(gB + (size_t)row * C_DIM + kt + lc),
                    (AS3 void*)&Bl[chunk * 512], 16, 0, 0);
            }
        } else {
            // ---- reg-staged f32 -> bf16 conversion (padded LDS) ----
            #pragma unroll
            for (int i = 0; i < 4; ++i) {
                int row = r8 + 32 * i;
                const float4* pa = (const float4*)(A + (size_t)row * C_DIM + kt + c8 * 8);
                float4 a0 = pa[0], a1 = pa[1];
                const float4* pb = (const float4*)(B + (size_t)row * C_DIM + kt + c8 * 8);
                float4 b0 = pb[0], b1 = pb[1];
                bf16x8 av, bv;
                av[0]=(__bf16)a0.x; av[1]=(__bf16)a0.y; av[2]=(__bf16)a0.z; av[3]=(__bf16)a0.w;
                av[4]=(__bf16)a1.x; av[5]=(__bf16)a1.y; av[6]=(__bf16)a1.z; av[7]=(__bf16)a1.w;
                bv[0]=(__bf16)b0.x; bv[1]=(__bf16)b0.y; bv[2]=(__bf16)b0.z; bv[3]=(__bf16)b0.w;
                bv[4]=(__bf16)b1.x; bv[5]=(__bf16)b1.y; bv[6]=(__bf16)b1.z; bv[7]=(__bf16)b1.w;
                *(bf16x8*)&Al[row * LDST + c8 * 8] = av;
                *(bf16x8*)&Bl[row * LDST + c8 * 8] = bv;
            }
        }
        __syncthreads();
        #pragma unroll
        for (int k2 = 0; k2 < 2; ++k2) {
            // PRE: swizzled read — slot (k2*4+q) XOR (row&7 == l15&7)
            int off;
            if constexpr (PRE) off = ((k2 * 4 + q) ^ (l15 & 7)) * 8;
            else               off = k2 * 32 + q * 8;
            bf16x8 af[4], bfv[4];
            #pragma unroll
            for (int mf = 0; mf < 4; ++mf)
                af[mf] = *(const bf16x8*)&Al[(wm * 64 + mf * 16 + l15) * LDST + off];
            #pragma unroll
            for (int nf = 0; nf < 4; ++nf)
                bfv[nf] = *(const bf16x8*)&Bl[(wn * 64 + nf * 16 + l15) * LDST + off];
            #pragma unroll
            for (int mf = 0; mf < 4; ++mf)
                #pragma unroll
                for (int nf = 0; nf < 4; ++nf)
                    acc[mf][nf] = __builtin_amdgcn_mfma_f32_16x16x32_bf16(
                        af[mf], bfv[nf], acc[mf][nf], 0, 0, 0);
        }
        __syncthreads();
    }

    if constexpr (MODE == 0) {
        // ---- e = exp(sim*scale); fused row/col sums only ----
        const float scale = 0.0390625f;   // (1/256)/0.1
        #pragma unroll
        for (int mf = 0; mf < 4; ++mf)
            #pragma unroll
            for (int nf = 0; nf < 4; ++nf)
                #pragma unroll
                for (int reg = 0; reg < 4; ++reg)
                    acc[mf][nf][reg] = __expf(acc[mf][nf][reg] * scale);

        {   // row sums: sum over nf, reduce over l15
            float rp[4][4];
            #pragma unroll
            for (int mf = 0; mf < 4; ++mf)
                #pragma unroll
                for (int reg = 0; reg < 4; ++reg) {
                    float v = acc[mf][0][reg] + acc[mf][1][reg] + acc[mf][2][reg] + acc[mf][3][reg];
                    v += __shfl_xor(v, 1); v += __shfl_xor(v, 2);
                    v += __shfl_xor(v, 4); v += __shfl_xor(v, 8);
                    rp[mf][reg] = v;
                }
            if (l15 == 0) {
                #pragma unroll
                for (int mf = 0; mf < 4; ++mf)
                    #pragma unroll
                    for (int reg = 0; reg < 4; ++reg)
                        atomicAdd(&rsum[n * L_DIM + tl * 128 + wm * 64 + mf * 16 + q * 4 + reg],
                                  rp[mf][reg]);
            }
        }
        {   // col sums: sum over mf,reg, reduce over q
            float cp[4];
            #pragma unroll
            for (int nf = 0; nf < 4; ++nf) {
                float v = 0.f;
                #pragma unroll
                for (int mf = 0; mf < 4; ++mf)
                    #pragma unroll
                    for (int reg = 0; reg < 4; ++reg)
                        v += acc[mf][nf][reg];
                v += __shfl_xor(v, 16); v += __shfl_xor(v, 32);
                cp[nf] = v;
            }
            if (q == 0) {
                #pragma unroll
                for (int nf = 0; nf < 4; ++nf)
                    atomicAdd(&csum[n * L_DIM + ts * 128 + wn * 64 + nf * 16 + l15], cp[nf]);
            }
        }
    } else {
        // ---- conf = exp(2*scale*sim) * invr * invc (recip fused in) ----
        const float scale2 = 0.078125f;   // 2*(1/256)/0.1
        float vr[4][4];
        #pragma unroll
        for (int mf = 0; mf < 4; ++mf)
            #pragma unroll
            for (int reg = 0; reg < 4; ++reg)
                vr[mf][reg] = 1.0f / rsum[n * L_DIM + tl * 128 + wm * 64 + mf * 16 + q * 4 + reg];
        float vc[4];
        #pragma unroll
        for (int nf = 0; nf < 4; ++nf)
            vc[nf] = 1.0f / csum[n * L_DIM + ts * 128 + wn * 64 + nf * 16 + l15];

        #pragma unroll
        for (int mf = 0; mf < 4; ++mf)
            #pragma unroll
            for (int nf = 0; nf < 4; ++nf)
                #pragma unroll
                for (int reg = 0; reg < 4; ++reg)
                    acc[mf][nf][reg] =
                        __expf(acc[mf][nf][reg] * scale2) * vr[mf][reg] * vc[nf];

        // ---- conf stores first: VMEM drains under the shuffle reductions ----
        float* Eb = E + (size_t)n * L_DIM * L_DIM + (size_t)tl * 128 * L_DIM + (size_t)ts * 128;
        #pragma unroll
        for (int mf = 0; mf < 4; ++mf) {
            #pragma unroll
            for (int nf = 0; nf < 4; ++nf) {
                int col = wn * 64 + nf * 16 + l15;
                #pragma unroll
                for (int reg = 0; reg < 4; ++reg) {
                    int row = wm * 64 + mf * 16 + q * 4 + reg;
                    Eb[(size_t)row * L_DIM + col] = acc[mf][nf][reg];
                }
            }
        }

        // ---- packed row max (value<<32 | ~col: ties -> smallest col) ----
        #pragma unroll
        for (int mf = 0; mf < 4; ++mf) {
            #pragma unroll
            for (int reg = 0; reg < 4; ++reg) {
                unsigned long long best = 0ull;
                #pragma unroll
                for (int nf = 0; nf < 4; ++nf) {
                    unsigned int cb = __float_as_uint(acc[mf][nf][reg]); // cf>0
                    unsigned int col = (unsigned int)(ts * 128 + wn * 64 + nf * 16 + l15);
                    unsigned long long p = ((unsigned long long)cb << 32) | (unsigned int)(~col);
                    best = p > best ? p : best;
                }
                #pragma unroll
                for (int m = 1; m < 16; m <<= 1) {
                    unsigned int hi = (unsigned int)(best >> 32), lo = (unsigned int)best;
                    hi = __shfl_xor(hi, m); lo = __shfl_xor(lo, m);
                    unsigned long long o = ((unsigned long long)hi << 32) | lo;
                    best = o > best ? o : best;
                }
                if (l15 == 0)
                    atomicMax(&rowpack[n * L_DIM + tl * 128 + wm * 64 + mf * 16 + q * 4 + reg],
                              best);
            }
        }
        // ---- col max ----
        #pragma unroll
        for (int nf = 0; nf < 4; ++nf) {
            float m0 = acc[0][nf][0];
            #pragma unroll
            for (int mf = 0; mf < 4; ++mf)
                #pragma unroll
                for (int reg = 0; reg < 4; ++reg)
                    m0 = fmaxf(m0, acc[mf][nf][reg]);
            unsigned int cb = __float_as_uint(m0);
            unsigned int o = __shfl_xor(cb, 16); cb = o > cb ? o : cb;
            o = __shfl_xor(cb, 32); cb = o > cb ? o : cb;
            if (q == 0)
                atomicMax(&colmax[n * L_DIM + ts * 128 + wn * 64 + nf * 16 + l15], cb);
        }
    }
}

// ---------------- K4: matching outputs ----------------
__global__ void final_k(const unsigned long long* __restrict__ rowpack,
                        const unsigned int* __restrict__ colmax,
                        float* __restrict__ mask_out, float* __restrict__ j_out,
                        float* __restrict__ mconf_out) {
    int i = blockIdx.x * 256 + threadIdx.x;
    if (i >= NB * L_DIM) return;
    int n = i >> 12, l = i & 4095;
    unsigned long long rp = rowpack[i];
    float v = __uint_as_float((unsigned int)(rp >> 32));
    int s = (int)(~(unsigned int)(rp & 0xFFFFFFFFull));
    float cv = __uint_as_float(colmax[n * L_DIM + s]);
    int lh = l >> 6, lw = l & 63;
    int sh = s >> 6, sw = s & 63;
    bool bl = (lh >= 2) && (lh < 62) && (lw >= 2) && (lw < 62);
    bool bs = (sh >= 2) && (sh < 62) && (sw >= 2) && (sw < 62);
    bool m = (v > 0.2f) && bl && bs && (v == cv);
    mask_out[i]  = m ? 1.0f : 0.0f;
    j_out[i]     = m ? (float)s : 0.0f;
    mconf_out[i] = m ? v : 0.0f;
}

extern "C" void kernel_launch(void* const* d_in, const int* in_sizes, int n_in,
                              void* d_out, int out_size, void* d_ws, size_t ws_size,
                              hipStream_t stream) {
    const float* f0 = (const float*)d_in[0];
    const float* f1 = (const float*)d_in[1];

    float* out_conf  = (float*)d_out;                       // [4,4096,4096]
    float* out_mask  = out_conf + (size_t)NB * L_DIM * L_DIM;
    float* out_j     = out_mask + NB * L_DIM;
    float* out_mconf = out_j + NB * L_DIM;

    float* rsum = (float*)d_ws;                                       //  64 KB
    float* csum = rsum + NB * L_DIM;                                  //  64 KB
    unsigned int* colmax = (unsigned int*)(csum + NB * L_DIM);        //  64 KB
    unsigned long long* rowpack = (unsigned long long*)(colmax + NB * L_DIM); // 128 KB

    // bf16 stash inside out_conf: last NB*L*C floats = 16.8 MB = n=3 rows
    // 3072..4095 (tiles tl 24..31). Overwritten with real conf by the tail.
    size_t stash_off = (size_t)NB * L_DIM * L_DIM - (size_t)NB * L_DIM * C_DIM;
    __bf16* abf = (__bf16*)(out_conf + stash_off);
    __bf16* bbf = abf + (size_t)NB * L_DIM * C_DIM;

    init_ws<<<dim3(64), dim3(256), 0, stream>>>(rsum, csum, colmax, rowpack);
    conv_k<<<dim3(2048, 2), dim3(256), 0, stream>>>(f0, f1, abf, bbf);
    gemm_pass<true, 0><<<dim3(32, 32, NB), dim3(256), 0, stream>>>(
        f0, f1, abf, bbf, nullptr, rsum, csum, nullptr, nullptr);
    gemm_pass<true, 1><<<dim3(32, 120, 1), dim3(256), 0, stream>>>(
        f0, f1, abf, bbf, out_conf, rsum, csum, rowpack, colmax);
    gemm_pass<false, 1><<<dim3(32, 8, 1), dim3(256), 0, stream>>>(
        f0, f1, nullptr, nullptr, out_conf, rsum, csum, rowpack, colmax);
    final_k<<<dim3(64), dim3(256), 0, stream>>>(rowpack, colmax, out_mask, out_j, out_mconf);
}

// Round 4
// 422.484 us; speedup vs baseline: 1.1408x; 1.1408x over previous
//
#include <hip/hip_runtime.h>

#define L_DIM 4096
#define C_DIM 256
#define NB 4

typedef __bf16 bf16x8 __attribute__((ext_vector_type(8)));
typedef float f32x4 __attribute__((ext_vector_type(4)));

#define GLB __attribute__((address_space(1)))
#define AS3 __attribute__((address_space(3)))

// ---------------- K0: f32 -> bf16 pre-conversion + fused ws zeroing --------
// grid (2048, 2): y selects matrix; blocks y==0,x<80 also zero the 320 KB
// accumulator region (rsum/csum/colmax/rowpack) — done before gemm0 starts.
__global__ __launch_bounds__(256) void conv_k(const float* __restrict__ f0,
                                              const float* __restrict__ f1,
                                              __bf16* __restrict__ abf,
                                              __bf16* __restrict__ bbf,
                                              float* __restrict__ ws_zero) {
    int i = blockIdx.x * 256 + threadIdx.x;   // 2048 x-blocks cover NB*L*C/8
    if (blockIdx.y == 0 && blockIdx.x < 80) { // 80*256*4 floats = 320 KB
        int j = (blockIdx.x * 256 + threadIdx.x) * 4;
        *(f32x4*)&ws_zero[j] = (f32x4){0.f, 0.f, 0.f, 0.f};
    }
    const float* in = blockIdx.y ? f1 : f0;
    __bf16* out = blockIdx.y ? bbf : abf;
    const float4* p = (const float4*)in + (size_t)i * 2;
    float4 a = p[0], b = p[1];
    bf16x8 v;
    v[0]=(__bf16)a.x; v[1]=(__bf16)a.y; v[2]=(__bf16)a.z; v[3]=(__bf16)a.w;
    v[4]=(__bf16)b.x; v[5]=(__bf16)b.y; v[6]=(__bf16)b.z; v[7]=(__bf16)b.w;
    *(bf16x8*)&out[(size_t)i * 8] = v;
}

// ---------------- GEMM (recompute) template ----------------
// Swapped-operand MFMA: acc[mf][nf][reg] = sim[row][col] with
//   row = wm*64 + mf*16 + l15          (lane-resident, fixed per thread)
//   col = wn*64 + nf*16 + q*4 + reg    (4 consecutive cols per f32x4!)
// -> MODE1 conf stores are 16x global_store_dwordx4 per thread.
// MODE: 0 -> e=exp(sim*scale), fused row/col atomicAdd sums (no matrix write)
//       1 -> conf = exp(2*scale*sim)*invr*invc, write conf, fused maxes
template<int MODE>
__global__ __launch_bounds__(256) void gemm_pass(
        const __bf16* __restrict__ a_bf, const __bf16* __restrict__ b_bf,
        float* __restrict__ E,
        float* __restrict__ rsum, float* __restrict__ csum,
        unsigned long long* __restrict__ rowpack, unsigned int* __restrict__ colmax) {
    const int ts = blockIdx.x;
    const int tl = blockIdx.y;
    const int n  = blockIdx.z;

    __shared__ __bf16 Al[128 * 64];
    __shared__ __bf16 Bl[128 * 64];

    const int t    = threadIdx.x;
    const int lane = t & 63;
    const int wave = t >> 6;
    const int wm   = wave >> 1, wn = wave & 1;
    const int q    = lane >> 4;
    const int l15  = lane & 15;

    const __bf16* gA = a_bf + ((size_t)n * L_DIM + (size_t)tl * 128) * C_DIM;
    const __bf16* gB = b_bf + ((size_t)n * L_DIM + (size_t)ts * 128) * C_DIM;

    f32x4 acc[4][4] = {};

    const int lr = lane >> 3;               // staging row-in-chunk (== row & 7)
    // rule #21: inverse-swizzled GLOBAL source column; linear LDS write +
    // swizzled ds_read compose to identity. slot' = slot ^ (row&7).
    const int lc = ((lane & 7) ^ lr) * 8;   // bf16 elems within 64-col slab

    for (int kt = 0; kt < C_DIM; kt += 64) {
        // ---- direct global->LDS staging, 16B/lane, linear LDS dest ----
        #pragma unroll
        for (int i = 0; i < 4; ++i) {
            const int chunk = wave * 4 + i;       // 1KB LDS chunk per call
            const int row = chunk * 8 + lr;
            __builtin_amdgcn_global_load_lds(
                (const GLB void*)(gA + (size_t)row * C_DIM + kt + lc),
                (AS3 void*)&Al[chunk * 512], 16, 0, 0);
            __builtin_amdgcn_global_load_lds(
                (const GLB void*)(gB + (size_t)row * C_DIM + kt + lc),
                (AS3 void*)&Bl[chunk * 512], 16, 0, 0);
        }
        __syncthreads();
        #pragma unroll
        for (int k2 = 0; k2 < 2; ++k2) {
            // swizzled read — slot (k2*4+q) XOR (row&7 == l15&7)
            const int off = ((k2 * 4 + q) ^ (l15 & 7)) * 8;
            bf16x8 af[4], bfv[4];
            #pragma unroll
            for (int mf = 0; mf < 4; ++mf)
                af[mf] = *(const bf16x8*)&Al[(wm * 64 + mf * 16 + l15) * 64 + off];
            #pragma unroll
            for (int nf = 0; nf < 4; ++nf)
                bfv[nf] = *(const bf16x8*)&Bl[(wn * 64 + nf * 16 + l15) * 64 + off];
            // swapped operands: D-row space = B rows (sim cols), D-col = l15 = sim row
            #pragma unroll
            for (int mf = 0; mf < 4; ++mf)
                #pragma unroll
                for (int nf = 0; nf < 4; ++nf)
                    acc[mf][nf] = __builtin_amdgcn_mfma_f32_16x16x32_bf16(
                        bfv[nf], af[mf], acc[mf][nf], 0, 0, 0);
        }
        __syncthreads();
    }

    if constexpr (MODE == 0) {
        // ---- e = exp(sim*scale); fused row/col sums only ----
        const float scale = 0.0390625f;   // (1/256)/0.1
        #pragma unroll
        for (int mf = 0; mf < 4; ++mf)
            #pragma unroll
            for (int nf = 0; nf < 4; ++nf)
                #pragma unroll
                for (int reg = 0; reg < 4; ++reg)
                    acc[mf][nf][reg] = __expf(acc[mf][nf][reg] * scale);

        // row sums: row = wm*64+mf*16+l15; in-thread sum over nf,reg; reduce over q
        #pragma unroll
        for (int mf = 0; mf < 4; ++mf) {
            float v = 0.f;
            #pragma unroll
            for (int nf = 0; nf < 4; ++nf)
                #pragma unroll
                for (int reg = 0; reg < 4; ++reg)
                    v += acc[mf][nf][reg];
            v += __shfl_xor(v, 16); v += __shfl_xor(v, 32);
            if (q == 0)
                atomicAdd(&rsum[n * L_DIM + tl * 128 + wm * 64 + mf * 16 + l15], v);
        }
        // col sums: col = wn*64+nf*16+q*4+reg; in-thread sum over mf; reduce over l15
        #pragma unroll
        for (int nf = 0; nf < 4; ++nf)
            #pragma unroll
            for (int reg = 0; reg < 4; ++reg) {
                float v = acc[0][nf][reg] + acc[1][nf][reg] + acc[2][nf][reg] + acc[3][nf][reg];
                v += __shfl_xor(v, 1); v += __shfl_xor(v, 2);
                v += __shfl_xor(v, 4); v += __shfl_xor(v, 8);
                if (l15 == 0)
                    atomicAdd(&csum[n * L_DIM + ts * 128 + wn * 64 + nf * 16 + q * 4 + reg], v);
            }
    } else {
        // ---- conf = exp(2*scale*sim) * invr * invc ----
        const float scale2 = 0.078125f;   // 2*(1/256)/0.1
        float vr[4];
        #pragma unroll
        for (int mf = 0; mf < 4; ++mf)
            vr[mf] = __builtin_amdgcn_rcpf(
                rsum[n * L_DIM + tl * 128 + wm * 64 + mf * 16 + l15]);
        float vc[4][4];
        #pragma unroll
        for (int nf = 0; nf < 4; ++nf)
            #pragma unroll
            for (int reg = 0; reg < 4; ++reg)
                vc[nf][reg] = __builtin_amdgcn_rcpf(
                    csum[n * L_DIM + ts * 128 + wn * 64 + nf * 16 + q * 4 + reg]);

        #pragma unroll
        for (int mf = 0; mf < 4; ++mf)
            #pragma unroll
            for (int nf = 0; nf < 4; ++nf)
                #pragma unroll
                for (int reg = 0; reg < 4; ++reg)
                    acc[mf][nf][reg] =
                        __expf(acc[mf][nf][reg] * scale2) * vr[mf] * vc[nf][reg];

        // ---- vectorized conf stores FIRST (drain under the reductions) ----
        float* Eb = E + (size_t)n * L_DIM * L_DIM + (size_t)tl * 128 * L_DIM + (size_t)ts * 128;
        #pragma unroll
        for (int mf = 0; mf < 4; ++mf) {
            const size_t rowoff = (size_t)(wm * 64 + mf * 16 + l15) * L_DIM;
            #pragma unroll
            for (int nf = 0; nf < 4; ++nf)
                *(f32x4*)&Eb[rowoff + wn * 64 + nf * 16 + q * 4] = acc[mf][nf];
        }

        // ---- packed row max (value<<32 | ~col: ties -> smallest col) ----
        #pragma unroll
        for (int mf = 0; mf < 4; ++mf) {
            unsigned long long best = 0ull;
            #pragma unroll
            for (int nf = 0; nf < 4; ++nf)
                #pragma unroll
                for (int reg = 0; reg < 4; ++reg) {
                    unsigned int cb = __float_as_uint(acc[mf][nf][reg]); // cf>0
                    unsigned int col = (unsigned int)(ts * 128 + wn * 64 + nf * 16 + q * 4 + reg);
                    unsigned long long p = ((unsigned long long)cb << 32) | (unsigned int)(~col);
                    best = p > best ? p : best;
                }
            #pragma unroll
            for (int m = 16; m < 64; m <<= 1) {   // reduce over q
                unsigned int hi = (unsigned int)(best >> 32), lo = (unsigned int)best;
                hi = __shfl_xor(hi, m); lo = __shfl_xor(lo, m);
                unsigned long long o = ((unsigned long long)hi << 32) | lo;
                best = o > best ? o : best;
            }
            if (q == 0)
                atomicMax(&rowpack[n * L_DIM + tl * 128 + wm * 64 + mf * 16 + l15], best);
        }
        // ---- col max: reduce over l15 ----
        #pragma unroll
        for (int nf = 0; nf < 4; ++nf)
            #pragma unroll
            for (int reg = 0; reg < 4; ++reg) {
                float m0 = fmaxf(fmaxf(acc[0][nf][reg], acc[1][nf][reg]),
                                 fmaxf(acc[2][nf][reg], acc[3][nf][reg]));
                unsigned int cb = __float_as_uint(m0);
                #pragma unroll
                for (int m = 1; m < 16; m <<= 1) {
                    unsigned int o = __shfl_xor(cb, m);
                    cb = o > cb ? o : cb;
                }
                if (l15 == 0)
                    atomicMax(&colmax[n * L_DIM + ts * 128 + wn * 64 + nf * 16 + q * 4 + reg], cb);
            }
    }
}

// ---------------- K4: matching outputs ----------------
__global__ void final_k(const unsigned long long* __restrict__ rowpack,
                        const unsigned int* __restrict__ colmax,
                        float* __restrict__ mask_out, float* __restrict__ j_out,
                        float* __restrict__ mconf_out) {
    int i = blockIdx.x * 256 + threadIdx.x;
    if (i >= NB * L_DIM) return;
    int n = i >> 12, l = i & 4095;
    unsigned long long rp = rowpack[i];
    float v = __uint_as_float((unsigned int)(rp >> 32));
    int s = (int)(~(unsigned int)(rp & 0xFFFFFFFFull));
    float cv = __uint_as_float(colmax[n * L_DIM + s]);
    int lh = l >> 6, lw = l & 63;
    int sh = s >> 6, sw = s & 63;
    bool bl = (lh >= 2) && (lh < 62) && (lw >= 2) && (lw < 62);
    bool bs = (sh >= 2) && (sh < 62) && (sw >= 2) && (sw < 62);
    bool m = (v > 0.2f) && bl && bs && (v == cv);
    mask_out[i]  = m ? 1.0f : 0.0f;
    j_out[i]     = m ? (float)s : 0.0f;
    mconf_out[i] = m ? v : 0.0f;
}

extern "C" void kernel_launch(void* const* d_in, const int* in_sizes, int n_in,
                              void* d_out, int out_size, void* d_ws, size_t ws_size,
                              hipStream_t stream) {
    const float* f0 = (const float*)d_in[0];
    const float* f1 = (const float*)d_in[1];

    float* out_conf  = (float*)d_out;                       // [4,4096,4096]
    float* out_mask  = out_conf + (size_t)NB * L_DIM * L_DIM;
    float* out_j     = out_mask + NB * L_DIM;
    float* out_mconf = out_j + NB * L_DIM;

    float* rsum = (float*)d_ws;                                       //  64 KB
    float* csum = rsum + NB * L_DIM;                                  //  64 KB
    unsigned int* colmax = (unsigned int*)(csum + NB * L_DIM);        //  64 KB
    unsigned long long* rowpack = (unsigned long long*)(colmax + NB * L_DIM); // 128 KB
    __bf16* abf = (__bf16*)(rowpack + NB * L_DIM);                    //   8 MB
    __bf16* bbf = abf + (size_t)NB * L_DIM * C_DIM;                   //   8 MB
    // ws_size >= 17 MB proven by rounds 1-2 (PRE path was active).

    conv_k<<<dim3(2048, 2), dim3(256), 0, stream>>>(f0, f1, abf, bbf, (float*)d_ws);
    gemm_pass<0><<<dim3(32, 32, NB), dim3(256), 0, stream>>>(
        abf, bbf, nullptr, rsum, csum, nullptr, nullptr);
    gemm_pass<1><<<dim3(32, 32, NB), dim3(256), 0, stream>>>(
        abf, bbf, out_conf, rsum, csum, rowpack, colmax);
    final_k<<<dim3(64), dim3(256), 0, stream>>>(rowpack, colmax, out_mask, out_j, out_mconf);
}